// Round 6
// baseline (969.816 us; speedup 1.0000x reference)
//
#include <hip/hip_runtime.h>
#include <cstddef>

#define B 64
#define NC 10
#define L 900
#define STASH_STRIDE 36000  // bytes: one full f32 out_map image slice (9000 floats)

// ---- K zero: clear cnt ----------------------------------------------------
__global__ void kz(int* __restrict__ cnt) {
  int i = blockIdx.x * 256 + threadIdx.x;
  if (i < B * NC) cnt[i] = 0;
}

// ---- K qkv: per-color q/k/v tables (1920 threads) -------------------------
__global__ void k_qkv(const float* __restrict__ embed, const float* __restrict__ ipw,
                      const float* __restrict__ ipb, float* __restrict__ qg,
                      float* __restrict__ kg, float* __restrict__ vg) {
  int i = blockIdx.x * 256 + threadIdx.x;
  if (i >= 1920) return;
  int c = i / 192, row = i % 192;
  float acc = ipb[row];
  for (int j = 0; j < 64; ++j) acc += embed[c * 64 + j] * ipw[row * 64 + j];
  int which = row >> 6, d = row & 63;
  if (which == 0) qg[c * 64 + d] = acc;
  else if (which == 1) kg[c * 64 + d] = acc;
  else vg[c * 64 + d] = acc;
}

// ---- K S: score table S[h][cq][ck] (400 threads) --------------------------
__global__ void k_S(const float* __restrict__ qg, const float* __restrict__ kg,
                    float* __restrict__ S) {
  int i = blockIdx.x * 256 + threadIdx.x;
  if (i >= 400) return;
  int h = i / 100, r = i % 100, cq = r / 10, ck = r % 10;
  float acc = 0.f;
  for (int e = 0; e < 16; ++e)
    acc += qg[cq * 64 + h * 16 + e] * kg[ck * 64 + h * 16 + e];
  S[i] = acc * 0.25f;
}

// ---- K idx: per-pixel argmax + histogram (57600 threads) ------------------
__global__ void k_idx2(const float* __restrict__ g, int* __restrict__ idx,
                       int* __restrict__ cnt) {
  int i = blockIdx.x * 256 + threadIdx.x;
  if (i >= B * L) return;
  int b = i / L, p = i % L;
  const float* gb = g + (size_t)b * NC * L;
  float best = gb[p]; int bi = 0;
  for (int c = 1; c < NC; ++c) {
    float v = gb[c * L + p];
    if (v > best) { best = v; bi = c; }
  }
  idx[i] = bi;
  atomicAdd(&cnt[b * NC + bi], 1);
}

// ---- K A: per-(b,h,cq) softmax row over colors (2560 threads) -------------
__global__ void k_A(const float* __restrict__ S, const int* __restrict__ cnt,
                    float* __restrict__ A) {
  int i = blockIdx.x * 256 + threadIdx.x;
  if (i >= B * 40) return;
  int b = i / 40, r = i % 40, h = r / 10, cq = r % 10;
  float m = -1e30f;
  for (int c = 0; c < NC; ++c)
    if (cnt[b * NC + c] > 0) m = fmaxf(m, S[h * 100 + cq * 10 + c]);
  float e[10]; float Z = 0.f;
  for (int c = 0; c < NC; ++c) {
    e[c] = expf(S[h * 100 + cq * 10 + c] - m);
    Z += (float)cnt[b * NC + c] * e[c];
  }
  float inv = 1.f / Z;
  for (int c = 0; c < NC; ++c)
    A[((b * 4 + h) * 10 + cq) * 10 + c] = e[c] * inv;
}

// ---- K CW: head-mean table (6400 threads) ---------------------------------
__global__ void k_CW(const float* __restrict__ A, float* __restrict__ CW) {
  int i = blockIdx.x * 256 + threadIdx.x;
  if (i >= B * 100) return;
  int b = i / 100, r = i % 100;
  float a = 0.f;
  for (int h = 0; h < 4; ++h) a += A[(b * 4 + h) * 100 + r];
  CW[i] = 0.25f * a;
}

// ---- K ctx: ctx[b][cq][dd] (40960 threads) --------------------------------
__global__ void k_ctx(const float* __restrict__ A, const int* __restrict__ cnt,
                      const float* __restrict__ vg, float* __restrict__ ctx) {
  int i = blockIdx.x * 256 + threadIdx.x;
  if (i >= B * 640) return;
  int b = i / 640, r = i % 640, cq = r >> 6, dd = r & 63, h = dd >> 4;
  float acc = 0.f;
  for (int ck = 0; ck < NC; ++ck)
    acc += A[((b * 4 + h) * 10 + cq) * 10 + ck] * (float)cnt[b * NC + ck] * vg[ck * 64 + dd];
  ctx[(b * 10 + cq) * 64 + dd] = acc;
}

// ---- K AT: out_proj (40960 threads) ---------------------------------------
__global__ void k_AT(const float* __restrict__ ctx, const float* __restrict__ opw,
                     const float* __restrict__ opb, float* __restrict__ AT) {
  int i = blockIdx.x * 256 + threadIdx.x;
  if (i >= B * 640) return;
  int b = i / 640, r = i % 640, cq = r >> 6, dd = r & 63;
  float acc = opb[dd];
  for (int e = 0; e < 64; ++e) acc += ctx[(b * 10 + cq) * 64 + e] * opw[dd * 64 + e];
  AT[(b * 10 + cq) * 64 + dd] = acc;
}

// ---- K c1: naive conv1 10->32 + relu --------------------------------------
__global__ void k_c1(const float* __restrict__ g, const float* __restrict__ w,
                     const float* __restrict__ bias, float* __restrict__ s1) {
  int i = blockIdx.x * 256 + threadIdx.x;
  if (i >= B * 32 * L) return;
  int b = i / (32 * L), oc = (i / L) % 32, p = i % L, oh = p / 30, ow = p % 30;
  float acc = bias[oc];
  for (int ic = 0; ic < 10; ++ic)
    for (int ky = 0; ky < 3; ++ky) {
      int y = oh + ky - 1;
      if (y < 0 || y >= 30) continue;
      for (int kx = 0; kx < 3; ++kx) {
        int x = ow + kx - 1;
        if (x < 0 || x >= 30) continue;
        acc += g[((size_t)(b * 10 + ic)) * L + y * 30 + x] * w[(oc * 10 + ic) * 9 + ky * 3 + kx];
      }
    }
  s1[i] = fmaxf(acc, 0.f);
}

// ---- K c2: naive conv2 32->64 + relu + AT add -----------------------------
__global__ void k_c2(const float* __restrict__ s1, const float* __restrict__ w,
                     const float* __restrict__ bias, const float* __restrict__ AT,
                     const int* __restrict__ idx, float* __restrict__ comb) {
  int i = blockIdx.x * 256 + threadIdx.x;
  if (i >= B * 64 * L) return;
  int b = i / (64 * L), oc = (i / L) % 64, p = i % L, oh = p / 30, ow = p % 30;
  float acc = bias[oc];
  for (int ic = 0; ic < 32; ++ic)
    for (int ky = 0; ky < 3; ++ky) {
      int y = oh + ky - 1;
      if (y < 0 || y >= 30) continue;
      for (int kx = 0; kx < 3; ++kx) {
        int x = ow + kx - 1;
        if (x < 0 || x >= 30) continue;
        acc += s1[((size_t)(b * 32 + ic)) * L + y * 30 + x] * w[(oc * 32 + ic) * 9 + ky * 3 + kx];
      }
    }
  int c = idx[b * L + p];
  comb[i] = fmaxf(acc, 0.f) + AT[(b * 10 + c) * 64 + oc];
}

// ---- K gf: global mean pool (4096 threads) --------------------------------
__global__ void k_gf2(const float* __restrict__ comb, float* __restrict__ gf) {
  int i = blockIdx.x * 256 + threadIdx.x;
  if (i >= B * 64) return;
  const float* src = comb + (size_t)i * L;
  float a = 0.f;
  for (int p = 0; p < L; ++p) a += src[p];
  gf[i] = a * (1.f / 900.f);
}

// ---- K mlp: 64->128->100, softmax + argmax (f32 out) ----------------------
__global__ void k_mlp(const float* __restrict__ gf, const float* __restrict__ l1w,
                      const float* __restrict__ l1b, const float* __restrict__ l2w,
                      const float* __restrict__ l2b, float* __restrict__ out_cm,
                      int* __restrict__ ncol) {
  int b = blockIdx.x, t = threadIdx.x;  // 128
  __shared__ float g[64], hmid[128], lg[100];
  if (t < 64) g[t] = gf[b * 64 + t];
  __syncthreads();
  {
    float acc = l1b[t];
    for (int j = 0; j < 64; ++j) acc += g[j] * l1w[t * 64 + j];
    hmid[t] = fmaxf(acc, 0.f);
  }
  __syncthreads();
  if (t < 100) {
    float acc = l2b[t];
    for (int j = 0; j < 128; ++j) acc += hmid[j] * l2w[t * 128 + j];
    lg[t] = acc;
  }
  __syncthreads();
  if (t < 10) {
    float m = lg[t * 10]; int am = 0;
    for (int j = 1; j < 10; ++j) {
      float v = lg[t * 10 + j];
      if (v > m) { m = v; am = j; }
    }
    float e[10]; float Z = 0.f;
    for (int j = 0; j < 10; ++j) { e[j] = expf(lg[t * 10 + j] - m); Z += e[j]; }
    float inv = 1.f / Z;
    for (int j = 0; j < 10; ++j) out_cm[(b * 10 + t) * 10 + j] = e[j] * inv;
    ncol[b * 10 + t] = am;
  }
}

// ---- K d1: naive convT(64->32) + BN + relu --------------------------------
__global__ void k_d1(const float* __restrict__ comb, const float* __restrict__ dw,
                     const float* __restrict__ db, const float* __restrict__ bng,
                     const float* __restrict__ bnb, float* __restrict__ d1) {
  int i = blockIdx.x * 256 + threadIdx.x;
  if (i >= B * 32 * L) return;
  int b = i / (32 * L), oc = (i / L) % 32, p = i % L, oh = p / 30, ow = p % 30;
  float acc = db[oc];
  for (int ic = 0; ic < 64; ++ic)
    for (int ky = 0; ky < 3; ++ky) {
      int y = oh + ky - 1;
      if (y < 0 || y >= 30) continue;
      for (int kx = 0; kx < 3; ++kx) {
        int x = ow + kx - 1;
        if (x < 0 || x >= 30) continue;
        // w1[oc][ic][ky][kx] = dec1_w[ic][oc][2-ky][2-kx]
        acc += comb[((size_t)(b * 64 + ic)) * L + y * 30 + x] *
               dw[((ic * 32 + oc) * 3 + (2 - ky)) * 3 + (2 - kx)];
      }
    }
  acc = acc * (1.f / sqrtf(1.f + 1e-5f)) * bng[oc] + bnb[oc];
  d1[i] = fmaxf(acc, 0.f);
}

// ---- K pred: 1x1 conv 32->10 (f32 out) ------------------------------------
__global__ void k_pred(const float* __restrict__ d1, const float* __restrict__ w2,
                       const float* __restrict__ b2, float* __restrict__ out0) {
  int i = blockIdx.x * 256 + threadIdx.x;
  if (i >= B * 10 * L) return;
  int b = i / (10 * L), o = (i / L) % 10, p = i % L;
  float acc = b2[o];
  for (int ic = 0; ic < 32; ++ic)
    acc += d1[((size_t)(b * 32 + ic)) * L + p] * w2[ic * 10 + o];
  out0[i] = acc;
}

// ---- K stash: {idx, ncol, CW} -> slice b of out_map region ----------------
// slice b = bytes [b*36000, b*36000+36000) of out_map; we use first 4040 B:
// [0,3600) idx ints, [3600,3640) ncol ints, [3640,4040) CW f32
__global__ void k_stash(const int* __restrict__ idx, const int* __restrict__ ncol,
                        const float* __restrict__ CW, unsigned char* __restrict__ stash) {
  int b = blockIdx.x, t = threadIdx.x;
  unsigned char* sl = stash + (size_t)b * STASH_STRIDE;
  int* sidx = (int*)sl;
  int* sncol = (int*)(sl + 3600);
  float* scw = (float*)(sl + 3640);
  for (int i = t; i < 900; i += 256) sidx[i] = idx[b * L + i];
  if (t < 10) sncol[t] = ncol[b * 10 + t];
  if (t < 100) scw[t] = CW[b * 100 + t];
}

// ---- K cw: broadcast color_weights [B,900,900] f32 ------------------------
__global__ void k_cw(const unsigned char* __restrict__ stash,
                     float* __restrict__ out2) {
  int blk = blockIdx.x;
  int b = blk / 60, rc = blk % 60;
  int t = threadIdx.x;
  const unsigned char* sl = stash + (size_t)b * STASH_STRIDE;
  const int* sidx = (const int*)sl;
  const float* scw = (const float*)(sl + 3640);
  __shared__ float lut[10][900];
  __shared__ unsigned char cols[900];
  __shared__ float cwb[100];
  for (int i = t; i < 900; i += 256) cols[i] = (unsigned char)sidx[i];
  for (int i = t; i < 100; i += 256) cwb[i] = scw[i];
  __syncthreads();
  for (int i = t; i < 9000; i += 256) {
    int cq = i / 900, p = i % 900;
    lut[cq][p] = cwb[cq * 10 + cols[p]];
  }
  __syncthreads();
  int base = rc * 15;
  for (int i = t; i < 15 * 225; i += 256) {
    int r = i / 225, ch = i % 225;
    int p = base + r;
    int cq = cols[p];
    float4 v = *(const float4*)&lut[cq][ch * 4];
    *(float4*)&out2[(size_t)b * 810000 + (size_t)p * 900 + ch * 4] = v;
  }
}

// ---- K map: one-hot mapped_output f32 -------------------------------------
// Block b reads ONLY its own stash slice, syncs, then overwrites ONLY its own
// out_map slice (same byte range) -> no cross-block hazard.
__global__ void k_map(const unsigned char* __restrict__ stash,
                      float* __restrict__ out4) {
  int b = blockIdx.x, t = threadIdx.x;
  const unsigned char* sl = stash + (size_t)b * STASH_STRIDE;
  const int* sidx = (const int*)sl;
  const int* sncol = (const int*)(sl + 3600);
  __shared__ unsigned char scol[900];
  __shared__ int sn[10];
  for (int i = t; i < 900; i += 256) scol[i] = (unsigned char)sidx[i];
  if (t < 10) sn[t] = sncol[t];
  __syncthreads();
  for (int i = t; i < 9000; i += 256) {
    int ch = i / 900, p = i % 900;
    out4[(size_t)b * 9000 + i] = (sn[scol[p]] == ch) ? 1.0f : 0.0f;
  }
}

extern "C" void kernel_launch(void* const* d_in, const int* in_sizes, int n_in,
                              void* d_out, int out_size, void* d_ws, size_t ws_size,
                              hipStream_t stream) {
  const float* input_grid = (const float*)d_in[0];
  const float* embed      = (const float*)d_in[1];
  const float* in_proj_w  = (const float*)d_in[2];
  const float* in_proj_b  = (const float*)d_in[3];
  const float* out_proj_w = (const float*)d_in[4];
  const float* out_proj_b = (const float*)d_in[5];
  const float* conv1_w    = (const float*)d_in[6];
  const float* conv1_b    = (const float*)d_in[7];
  const float* conv2_w    = (const float*)d_in[8];
  const float* conv2_b    = (const float*)d_in[9];
  const float* lin1_w     = (const float*)d_in[10];
  const float* lin1_b     = (const float*)d_in[11];
  const float* lin2_w     = (const float*)d_in[12];
  const float* lin2_b     = (const float*)d_in[13];
  const float* dec1_w     = (const float*)d_in[14];
  const float* dec1_b     = (const float*)d_in[15];
  const float* bn_g       = (const float*)d_in[16];
  const float* bn_b       = (const float*)d_in[17];
  const float* dec2_w     = (const float*)d_in[18];
  const float* dec2_b     = (const float*)d_in[19];

  // Output regions in f32 ELEMENTS
  float* out      = (float*)d_out;
  float* out_pred = out;                  // 576,000
  float* out_cmap = out + 576000;         // 6,400
  float* out_cw   = out + 582400;         // 51,840,000
  float* out_map  = out + 52422400;       // 576,000

  // Scratch inside out_cw region (dead until k_cw runs). ~30 MB used.
  float* cwf  = out_cw;
  float* comb = cwf;                          // 3,686,400
  float* s1   = cwf + 3686400;                // 1,843,200
  float* d1   = cwf + 5529600;                // 1,843,200
  float* AT   = cwf + 7372800;                // 40,960
  float* ctx  = cwf + 7413760;                // 40,960
  float* A    = cwf + 7454720;                // 25,600
  float* qg   = cwf + 7480320;                // 640
  float* kg   = cwf + 7480960;                // 640
  float* vg   = cwf + 7481600;                // 640
  float* S    = cwf + 7482240;                // 400
  float* CW   = cwf + 7482640;                // 6,400
  float* gf   = cwf + 7489040;                // 4,096
  int*   cnt  = (int*)(cwf + 7493136);        // 640
  int*   ncol = (int*)(cwf + 7493776);        // 640
  int*   idx  = (int*)(cwf + 7494416);        // 57,600
  unsigned char* stash = (unsigned char*)out_map;  // 64 slices x 36000 B (use 4040)

  kz<<<3, 256, 0, stream>>>(cnt);
  k_qkv<<<8, 256, 0, stream>>>(embed, in_proj_w, in_proj_b, qg, kg, vg);
  k_S<<<2, 256, 0, stream>>>(qg, kg, S);
  k_idx2<<<(B * L + 255) / 256, 256, 0, stream>>>(input_grid, idx, cnt);
  k_A<<<10, 256, 0, stream>>>(S, cnt, A);
  k_CW<<<25, 256, 0, stream>>>(A, CW);
  k_ctx<<<160, 256, 0, stream>>>(A, cnt, vg, ctx);
  k_AT<<<160, 256, 0, stream>>>(ctx, out_proj_w, out_proj_b, AT);
  k_c1<<<(B * 32 * L + 255) / 256, 256, 0, stream>>>(input_grid, conv1_w, conv1_b, s1);
  k_c2<<<(B * 64 * L + 255) / 256, 256, 0, stream>>>(s1, conv2_w, conv2_b, AT, idx, comb);
  k_gf2<<<16, 256, 0, stream>>>(comb, gf);
  k_mlp<<<B, 128, 0, stream>>>(gf, lin1_w, lin1_b, lin2_w, lin2_b, out_cmap, ncol);
  k_d1<<<(B * 32 * L + 255) / 256, 256, 0, stream>>>(comb, dec1_w, dec1_b, bn_g, bn_b, d1);
  k_pred<<<(B * 10 * L + 255) / 256, 256, 0, stream>>>(d1, dec2_w, dec2_b, out_pred);
  k_stash<<<B, 256, 0, stream>>>(idx, ncol, CW, stash);
  k_cw<<<B * 60, 256, 0, stream>>>(stash, out_cw);
  k_map<<<B, 256, 0, stream>>>(stash, out_map);
}

// Round 7
// 236.516 us; speedup vs baseline: 4.1004x; 4.1004x over previous
//
#include <hip/hip_runtime.h>
#include <cstddef>

#define B 64
#define NC 10
#define L 900
#define STASH_STRIDE 36000  // bytes: one full f32 out_map image slice (9000 floats)

// ---- K prep: transpose/scale conv weights, zero cnt -----------------------
// wt0[r][32]: conv1 (r=ic*9+kk, ic<10), wt2[r][64]: conv2 (r<288),
// wt1[r][32]: dec1 flipped+transposed+BN-scaled (r=ic*9+ky*3+kx, ic<64),
// bias1[32] = db*s + bnb
__global__ void k_prep(const float* __restrict__ cw1, const float* __restrict__ cw2,
                       const float* __restrict__ dw, const float* __restrict__ db,
                       const float* __restrict__ bng, const float* __restrict__ bnb,
                       float* __restrict__ wt0, float* __restrict__ wt2,
                       float* __restrict__ wt1, float* __restrict__ bias1,
                       int* __restrict__ cnt) {
  int i = blockIdx.x * 256 + threadIdx.x;
  if (i < 2880) {
    int r = i / 32, oc = i % 32;
    wt0[r * 32 + oc] = cw1[oc * 90 + r];
  } else if (i < 2880 + 18432) {
    int e = i - 2880, r = e / 64, oc = e % 64;
    wt2[r * 64 + oc] = cw2[oc * 288 + r];
  } else if (i < 2880 + 18432 + 18432) {
    int e = i - 2880 - 18432, r = e / 32, oc = e % 32;
    int ic = r / 9, kk = r % 9, ky = kk / 3, kx = kk % 3;
    float s = bng[oc] / sqrtf(1.f + 1e-5f);
    wt1[r * 32 + oc] = dw[((ic * 32 + oc) * 3 + (2 - ky)) * 3 + (2 - kx)] * s;
  } else if (i < 39744 + 32) {
    int oc = i - 39744;
    float s = bng[oc] / sqrtf(1.f + 1e-5f);
    bias1[oc] = db[oc] * s + bnb[oc];
  } else if (i < 39776 + B * NC) {
    cnt[i - 39776] = 0;
  }
}

// ---- K tables: per-color q/k/v + score table S[4][10][10] -----------------
__global__ void k_tables(const float* __restrict__ embed,
                         const float* __restrict__ ipw,
                         const float* __restrict__ ipb,
                         float* __restrict__ ve_g, float* __restrict__ S_g) {
  int t = threadIdx.x;
  __shared__ float emb[640], q[640], k[640];
  for (int i = t; i < 640; i += 256) emb[i] = embed[i];
  __syncthreads();
  for (int row = t; row < 192; row += 256) {
    int which = row >> 6, d = row & 63;
    for (int c = 0; c < 10; ++c) {
      float acc = ipb[row];
      for (int j = 0; j < 64; ++j) acc += emb[c * 64 + j] * ipw[row * 64 + j];
      if (which == 0) q[c * 64 + d] = acc;
      else if (which == 1) k[c * 64 + d] = acc;
      else ve_g[c * 64 + d] = acc;
    }
  }
  __syncthreads();
  for (int i = t; i < 400; i += 256) {
    int h = i / 100, r = i % 100, cq = r / 10, ck = r % 10;
    float acc = 0.f;
    for (int e = 0; e < 16; ++e)
      acc += q[cq * 64 + h * 16 + e] * k[ck * 64 + h * 16 + e];
    S_g[i] = acc * 0.25f;
  }
}

// ---- K idx: per-pixel argmax + histogram ----------------------------------
__global__ void k_idx2(const float* __restrict__ g, int* __restrict__ idx,
                       int* __restrict__ cnt) {
  int i = blockIdx.x * 256 + threadIdx.x;
  if (i >= B * L) return;
  int b = i / L, p = i % L;
  const float* gb = g + (size_t)b * NC * L;
  float best = gb[p]; int bi = 0;
  for (int c = 1; c < NC; ++c) {
    float v = gb[c * L + p];
    if (v > best) { best = v; bi = c; }
  }
  idx[i] = bi;
  atomicAdd(&cnt[b * NC + bi], 1);
}

// ---- K attn: per-image A, CW, ctx, AT (64 blocks x 128) -------------------
__global__ void k_attn(const float* __restrict__ S, const float* __restrict__ ve,
                       const int* __restrict__ cnt,
                       const float* __restrict__ opw, const float* __restrict__ opb,
                       float* __restrict__ CW, float* __restrict__ AT) {
  int b = blockIdx.x, t = threadIdx.x;  // 128 threads
  __shared__ float A[4][10][10];
  __shared__ float cf[10];
  __shared__ float ctx[10][64];
  if (t < 10) cf[t] = (float)cnt[b * 10 + t];
  __syncthreads();
  if (t < 40) {
    int h = t / 10, cq = t % 10;
    const float* Sr = S + (h * 10 + cq) * 10;
    float m = -1e30f;
    for (int c = 0; c < 10; ++c) if (cf[c] > 0.f) m = fmaxf(m, Sr[c]);
    float e[10]; float Z = 0.f;
    for (int c = 0; c < 10; ++c) { e[c] = expf(Sr[c] - m); Z += cf[c] * e[c]; }
    float inv = 1.f / Z;
    for (int c = 0; c < 10; ++c) A[h][cq][c] = e[c] * inv;
  }
  __syncthreads();
  if (t < 100) {
    int cq = t / 10, ck = t % 10;
    CW[b * 100 + t] = 0.25f * (A[0][cq][ck] + A[1][cq][ck] + A[2][cq][ck] + A[3][cq][ck]);
  }
  for (int i = t; i < 640; i += 128) {
    int cq = i >> 6, dd = i & 63, h = dd >> 4;
    float acc = 0.f;
    for (int ck = 0; ck < 10; ++ck) acc += A[h][cq][ck] * cf[ck] * ve[ck * 64 + dd];
    ctx[cq][dd] = acc;
  }
  __syncthreads();
  for (int i = t; i < 640; i += 128) {
    int cq = i >> 6, dd = i & 63;
    float acc = opb[dd];
    for (int e = 0; e < 64; ++e) acc += ctx[cq][e] * opw[dd * 64 + e];
    AT[(b * 10 + cq) * 64 + dd] = acc;
  }
}

// ---- K c1: conv1 10->32 + relu (tiled, row-pair blocks) -------------------
__global__ __launch_bounds__(256) void k_c1(const float* __restrict__ g,
                                            const float* __restrict__ wt0,
                                            const float* __restrict__ cb,
                                            float* __restrict__ s1) {
  int blk = blockIdx.x, b = blk / 15, pr = blk % 15, oh0 = pr * 2;
  int t = threadIdx.x;
  __shared__ float ins[4][10][34];
  for (int e = t; e < 1360; e += 256) {
    int r = e / 340, rem = e % 340, ic = rem / 34, x = rem % 34;
    int y = oh0 + r - 1, gx = x - 1;
    float v = 0.f;
    if (y >= 0 && y < 30 && gx >= 0 && gx < 30)
      v = g[(size_t)(b * 10 + ic) * 900 + y * 30 + gx];
    ins[r][ic][x] = v;
  }
  __syncthreads();
  int lane = t & 63, ow = lane & 31, rr = lane >> 5;
  int oc0 = __builtin_amdgcn_readfirstlane((t >> 6) * 8);
  float acc[8];
  #pragma unroll
  for (int j = 0; j < 8; ++j) acc[j] = cb[oc0 + j];
  for (int ic = 0; ic < 10; ++ic) {
    #pragma unroll
    for (int ky = 0; ky < 3; ++ky) {
      #pragma unroll
      for (int kx = 0; kx < 3; ++kx) {
        float iv = ins[rr + ky][ic][ow + kx];
        const float* wr = wt0 + (ic * 9 + ky * 3 + kx) * 32 + oc0;
        #pragma unroll
        for (int j = 0; j < 8; ++j) acc[j] = fmaf(iv, wr[j], acc[j]);
      }
    }
  }
  if (ow < 30) {
    #pragma unroll
    for (int j = 0; j < 8; ++j)
      s1[(size_t)(b * 32 + oc0 + j) * 900 + (oh0 + rr) * 30 + ow] = fmaxf(acc[j], 0.f);
  }
}

// ---- K c2: conv2 32->64 + relu + AT add (tiled) ---------------------------
__global__ __launch_bounds__(256) void k_c2(const float* __restrict__ s1,
                                            const float* __restrict__ wt2,
                                            const float* __restrict__ cb,
                                            const float* __restrict__ AT,
                                            const int* __restrict__ idx,
                                            float* __restrict__ comb) {
  int blk = blockIdx.x, b = blk / 15, pr = blk % 15, oh0 = pr * 2;
  int t = threadIdx.x;
  __shared__ float ins[4][32][34];
  for (int e = t; e < 4352; e += 256) {
    int r = e / 1088, rem = e % 1088, ic = rem / 34, x = rem % 34;
    int y = oh0 + r - 1, gx = x - 1;
    float v = 0.f;
    if (y >= 0 && y < 30 && gx >= 0 && gx < 30)
      v = s1[(size_t)(b * 32 + ic) * 900 + y * 30 + gx];
    ins[r][ic][x] = v;
  }
  __syncthreads();
  int lane = t & 63, ow = lane & 31, rr = lane >> 5;
  int oc0 = __builtin_amdgcn_readfirstlane((t >> 6) * 16);
  float acc[16];
  #pragma unroll
  for (int j = 0; j < 16; ++j) acc[j] = cb[oc0 + j];
  for (int ic = 0; ic < 32; ++ic) {
    #pragma unroll
    for (int ky = 0; ky < 3; ++ky) {
      #pragma unroll
      for (int kx = 0; kx < 3; ++kx) {
        float iv = ins[rr + ky][ic][ow + kx];
        const float* wr = wt2 + (ic * 9 + ky * 3 + kx) * 64 + oc0;
        #pragma unroll
        for (int j = 0; j < 16; ++j) acc[j] = fmaf(iv, wr[j], acc[j]);
      }
    }
  }
  if (ow < 30) {
    int c = idx[b * 900 + (oh0 + rr) * 30 + ow];
    const float* at = AT + ((size_t)b * 10 + c) * 64 + oc0;
    #pragma unroll
    for (int j = 0; j < 16; ++j)
      comb[(size_t)(b * 64 + oc0 + j) * 900 + (oh0 + rr) * 30 + ow] =
          fmaxf(acc[j], 0.f) + at[j];
  }
}

// ---- K gf3: global mean pool, one wave per (b,oc) -------------------------
__global__ void k_gf3(const float* __restrict__ comb, float* __restrict__ gf) {
  int wid = blockIdx.x * 4 + (threadIdx.x >> 6);  // b*64+oc
  int lane = threadIdx.x & 63;
  const float* src = comb + (size_t)wid * 900;
  float a = 0.f;
  for (int p = lane; p < 900; p += 64) a += src[p];
  for (int o = 32; o; o >>= 1) a += __shfl_down(a, o, 64);
  if (lane == 0) gf[wid] = a * (1.f / 900.f);
}

// ---- K mlp: 64->128->100, softmax + argmax --------------------------------
__global__ void k_mlp(const float* __restrict__ gf, const float* __restrict__ l1w,
                      const float* __restrict__ l1b, const float* __restrict__ l2w,
                      const float* __restrict__ l2b, float* __restrict__ out_cm,
                      int* __restrict__ ncol) {
  int b = blockIdx.x, t = threadIdx.x;  // 128
  __shared__ float g[64], hmid[128], lg[100];
  if (t < 64) g[t] = gf[b * 64 + t];
  __syncthreads();
  {
    float acc = l1b[t];
    for (int j = 0; j < 64; ++j) acc += g[j] * l1w[t * 64 + j];
    hmid[t] = fmaxf(acc, 0.f);
  }
  __syncthreads();
  if (t < 100) {
    float acc = l2b[t];
    for (int j = 0; j < 128; ++j) acc += hmid[j] * l2w[t * 128 + j];
    lg[t] = acc;
  }
  __syncthreads();
  if (t < 10) {
    float m = lg[t * 10]; int am = 0;
    for (int j = 1; j < 10; ++j) {
      float v = lg[t * 10 + j];
      if (v > m) { m = v; am = j; }
    }
    float e[10]; float Z = 0.f;
    for (int j = 0; j < 10; ++j) { e[j] = expf(lg[t * 10 + j] - m); Z += e[j]; }
    float inv = 1.f / Z;
    for (int j = 0; j < 10; ++j) out_cm[(b * 10 + t) * 10 + j] = e[j] * inv;
    ncol[b * 10 + t] = am;
  }
}

// ---- K d1: decoder convT(64->32)+BN+relu, fused 1x1 pred (tiled) ----------
__global__ __launch_bounds__(256) void k_d1(const float* __restrict__ comb,
                                            const float* __restrict__ wt1,
                                            const float* __restrict__ bias1,
                                            const float* __restrict__ w2,
                                            const float* __restrict__ b2,
                                            float* __restrict__ outp) {
  int blk = blockIdx.x, b = blk / 15, pr = blk % 15, oh0 = pr * 2;
  int t = threadIdx.x;
  __shared__ float ins[4][64][34];
  __shared__ float d1s[2][32][32];
  for (int e = t; e < 8704; e += 256) {
    int r = e / 2176, rem = e % 2176, ic = rem / 34, x = rem % 34;
    int y = oh0 + r - 1, gx = x - 1;
    float v = 0.f;
    if (y >= 0 && y < 30 && gx >= 0 && gx < 30)
      v = comb[(size_t)(b * 64 + ic) * 900 + y * 30 + gx];
    ins[r][ic][x] = v;
  }
  __syncthreads();
  int lane = t & 63, ow = lane & 31, rr = lane >> 5;
  int oc0 = __builtin_amdgcn_readfirstlane((t >> 6) * 8);
  float acc[8];
  #pragma unroll
  for (int j = 0; j < 8; ++j) acc[j] = bias1[oc0 + j];
  for (int ic = 0; ic < 64; ++ic) {
    #pragma unroll
    for (int ky = 0; ky < 3; ++ky) {
      #pragma unroll
      for (int kx = 0; kx < 3; ++kx) {
        float iv = ins[rr + ky][ic][ow + kx];
        const float* wr = wt1 + (ic * 9 + ky * 3 + kx) * 32 + oc0;
        #pragma unroll
        for (int j = 0; j < 8; ++j) acc[j] = fmaf(iv, wr[j], acc[j]);
      }
    }
  }
  if (ow < 30) {
    #pragma unroll
    for (int j = 0; j < 8; ++j) d1s[rr][oc0 + j][ow] = fmaxf(acc[j], 0.f);
  }
  __syncthreads();
  // fused 1x1 conv 32->10
  for (int e = t; e < 600; e += 256) {
    int r = e / 300, rem = e % 300, o = rem / 30, ow2 = rem % 30;
    float a2 = b2[o];
    #pragma unroll
    for (int ic = 0; ic < 32; ++ic) a2 += d1s[r][ic][ow2] * w2[ic * 10 + o];
    outp[(size_t)(b * 10 + o) * 900 + (oh0 + r) * 30 + ow2] = a2;
  }
}

// ---- K stash: {idx, ncol, CW} -> slice b of out_map region ----------------
__global__ void k_stash(const int* __restrict__ idx, const int* __restrict__ ncol,
                        const float* __restrict__ CW, unsigned char* __restrict__ stash) {
  int b = blockIdx.x, t = threadIdx.x;
  unsigned char* sl = stash + (size_t)b * STASH_STRIDE;
  int* sidx = (int*)sl;
  int* sncol = (int*)(sl + 3600);
  float* scw = (float*)(sl + 3640);
  for (int i = t; i < 900; i += 256) sidx[i] = idx[b * L + i];
  if (t < 10) sncol[t] = ncol[b * 10 + t];
  if (t < 100) scw[t] = CW[b * 100 + t];
}

// ---- K cw: broadcast color_weights [B,900,900] f32 ------------------------
__global__ void k_cw(const unsigned char* __restrict__ stash,
                     float* __restrict__ out2) {
  int blk = blockIdx.x;
  int b = blk / 60, rc = blk % 60;
  int t = threadIdx.x;
  const unsigned char* sl = stash + (size_t)b * STASH_STRIDE;
  const int* sidx = (const int*)sl;
  const float* scw = (const float*)(sl + 3640);
  __shared__ float lut[10][900];
  __shared__ unsigned char cols[900];
  __shared__ float cwb[100];
  for (int i = t; i < 900; i += 256) cols[i] = (unsigned char)sidx[i];
  for (int i = t; i < 100; i += 256) cwb[i] = scw[i];
  __syncthreads();
  for (int i = t; i < 9000; i += 256) {
    int cq = i / 900, p = i % 900;
    lut[cq][p] = cwb[cq * 10 + cols[p]];
  }
  __syncthreads();
  int base = rc * 15;
  for (int i = t; i < 15 * 225; i += 256) {
    int r = i / 225, ch = i % 225;
    int p = base + r;
    int cq = cols[p];
    float4 v = *(const float4*)&lut[cq][ch * 4];
    *(float4*)&out2[(size_t)b * 810000 + (size_t)p * 900 + ch * 4] = v;
  }
}

// ---- K map: one-hot mapped_output f32 -------------------------------------
__global__ void k_map(const unsigned char* __restrict__ stash,
                      float* __restrict__ out4) {
  int b = blockIdx.x, t = threadIdx.x;
  const unsigned char* sl = stash + (size_t)b * STASH_STRIDE;
  const int* sidx = (const int*)sl;
  const int* sncol = (const int*)(sl + 3600);
  __shared__ unsigned char scol[900];
  __shared__ int sn[10];
  for (int i = t; i < 900; i += 256) scol[i] = (unsigned char)sidx[i];
  if (t < 10) sn[t] = sncol[t];
  __syncthreads();
  for (int i = t; i < 9000; i += 256) {
    int ch = i / 900, p = i % 900;
    out4[(size_t)b * 9000 + i] = (sn[scol[p]] == ch) ? 1.0f : 0.0f;
  }
}

extern "C" void kernel_launch(void* const* d_in, const int* in_sizes, int n_in,
                              void* d_out, int out_size, void* d_ws, size_t ws_size,
                              hipStream_t stream) {
  const float* input_grid = (const float*)d_in[0];
  const float* embed      = (const float*)d_in[1];
  const float* in_proj_w  = (const float*)d_in[2];
  const float* in_proj_b  = (const float*)d_in[3];
  const float* out_proj_w = (const float*)d_in[4];
  const float* out_proj_b = (const float*)d_in[5];
  const float* conv1_w    = (const float*)d_in[6];
  const float* conv1_b    = (const float*)d_in[7];
  const float* conv2_w    = (const float*)d_in[8];
  const float* conv2_b    = (const float*)d_in[9];
  const float* lin1_w     = (const float*)d_in[10];
  const float* lin1_b     = (const float*)d_in[11];
  const float* lin2_w     = (const float*)d_in[12];
  const float* lin2_b     = (const float*)d_in[13];
  const float* dec1_w     = (const float*)d_in[14];
  const float* dec1_b     = (const float*)d_in[15];
  const float* bn_g       = (const float*)d_in[16];
  const float* bn_b       = (const float*)d_in[17];
  const float* dec2_w     = (const float*)d_in[18];
  const float* dec2_b     = (const float*)d_in[19];

  // Output regions in f32 ELEMENTS
  float* out      = (float*)d_out;
  float* out_pred = out;                  // 576,000
  float* out_cmap = out + 576000;         // 6,400
  float* out_cw   = out + 582400;         // 51,840,000
  float* out_map  = out + 52422400;       // 576,000

  // Scratch inside out_cw region (dead until k_cw runs). ~22.7 MB used.
  float* cwf   = out_cw;
  float* comb  = cwf;                     // 3,686,400
  float* s1    = cwf + 3686400;           // 1,843,200
  float* AT    = cwf + 5529600;           // 40,960
  float* ve    = cwf + 5570560;           // 640
  float* S     = cwf + 5571200;           // 400
  float* CW    = cwf + 5571600;           // 6,400
  float* gf    = cwf + 5578000;           // 4,096
  float* wt0   = cwf + 5582096;           // 2,880
  float* wt2   = cwf + 5584976;           // 18,432
  float* wt1   = cwf + 5603408;           // 18,432
  float* bias1 = cwf + 5621840;           // 32
  int*   cnt   = (int*)(cwf + 5621872);   // 640
  int*   ncol  = (int*)(cwf + 5622512);   // 640
  int*   idx   = (int*)(cwf + 5623152);   // 57,600
  unsigned char* stash = (unsigned char*)out_map;  // 64 slices x 36000 B (use 4040)

  k_prep<<<158, 256, 0, stream>>>(conv1_w, conv2_w, dec1_w, dec1_b, bn_g, bn_b,
                                  wt0, wt2, wt1, bias1, cnt);
  k_tables<<<1, 256, 0, stream>>>(embed, in_proj_w, in_proj_b, ve, S);
  k_idx2<<<(B * L + 255) / 256, 256, 0, stream>>>(input_grid, idx, cnt);
  k_attn<<<B, 128, 0, stream>>>(S, ve, cnt, out_proj_w, out_proj_b, CW, AT);
  k_c1<<<B * 15, 256, 0, stream>>>(input_grid, wt0, conv1_b, s1);
  k_c2<<<B * 15, 256, 0, stream>>>(s1, wt2, conv2_b, AT, idx, comb);
  k_gf3<<<1024, 256, 0, stream>>>(comb, gf);
  k_mlp<<<B, 128, 0, stream>>>(gf, lin1_w, lin1_b, lin2_w, lin2_b, out_cmap, ncol);
  k_d1<<<B * 15, 256, 0, stream>>>(comb, wt1, bias1, dec2_w, dec2_b, out_pred);
  k_stash<<<B, 256, 0, stream>>>(idx, ncol, CW, stash);
  k_cw<<<B * 60, 256, 0, stream>>>(stash, out_cw);
  k_map<<<B, 256, 0, stream>>>(stash, out_map);
}